// Round 13
// baseline (7082.715 us; speedup 1.0000x reference)
//
#include <hip/hip_runtime.h>
#include <math.h>

#define NN 8192
#define MM 8192
#define FD 128
#define NITER 100
#define NPOLISH 4
#define RELTHR 1e-6f

typedef unsigned short ushort_t;

struct Consts {
  float inv_temp, B;
  float lmu_main, lmu_eps, lmu_dust;
  float lnu_main, lnu_eps, lnu_dust;
  int overlap;
};

__device__ __forceinline__ unsigned fenc(float f){
  unsigned u = __float_as_uint(f);
  return (u & 0x80000000u) ? ~u : (u | 0x80000000u);
}
__device__ __forceinline__ float fdec(unsigned e){
  return __uint_as_float((e & 0x80000000u) ? (e ^ 0x80000000u) : ~e);
}
__device__ __forceinline__ void lse_add(float& m, float& s, float x){
  float nm = fmaxf(m, x);
  s = s * __expf(m - nm) + __expf(x - nm);
  m = nm;
}
__device__ __forceinline__ void lse_merge(float& m, float& s, float mo, float so){
  float nm = fmaxf(m, mo);
  s = s * __expf(m - nm) + so * __expf(mo - nm);
  m = nm;
}
__device__ __forceinline__ void block_lse_reduce(float& m, float& s, float* rm, float* rs, int t){
  #pragma unroll
  for (int off = 32; off; off >>= 1){
    float mo = __shfl_down(m, off);
    float so = __shfl_down(s, off);
    lse_merge(m, s, mo, so);
  }
  if ((t & 63) == 0){ rm[t >> 6] = m; rs[t >> 6] = s; }
  __syncthreads();
  if (t == 0){
    m = rm[0]; s = rs[0];
    #pragma unroll
    for (int w = 1; w < 4; w++) lse_merge(m, s, rm[w], rs[w]);
  }
}

// init: rowmax -> enc(-inf), rowmin -> enc(+inf), consts, se
__global__ void init_kernel(const float* lt, const float* db, const int* ovp,
                            Consts* C, unsigned* se, unsigned* rowmax, unsigned* rowmin){
  int b = blockIdx.x, t = threadIdx.x;
  if (b < 32){ rowmax[b * 256 + t] = fenc(-INFINITY); return; }
  if (b < 64){ rowmin[(b - 32) * 256 + t] = fenc(INFINITY); return; }
  if (t == 0){
    float temp = fmaxf(expf(lt[0]), 1e-9f);
    C->inv_temp = 1.0f / temp;
    C->B = db[0];
    int ov = ovp[0];
    C->overlap = ov;
    int us = NN - ov > 0 ? NN - ov : 0;
    int ut = MM - ov > 0 ? MM - ov : 0;
    float mud = (float)fmax((double)ut * 0.3, 1e-9);
    float nud = (float)fmax((double)us * 0.3, 1e-9);
    int ones_mu = us > 0 ? ov : NN;
    int ones_nu = ut > 0 ? ov : MM;
    double Zmu = (double)ones_mu + (double)(NN - ones_mu) * 1e-9 + (double)mud;
    double Znu = (double)ones_nu + (double)(MM - ones_nu) * 1e-9 + (double)nud;
    C->lmu_main = (float)log(1.0 / Zmu);
    C->lmu_eps  = (float)log(1e-9 / Zmu);
    C->lmu_dust = (float)log((double)mud / Zmu);
    C->lnu_main = (float)log(1.0 / Znu);
    C->lnu_eps  = (float)log(1e-9 / Znu);
    C->lnu_dust = (float)log((double)nud / Znu);
    *se = 0u;
  }
}

__global__ __launch_bounds__(128) void mlp_kernel(const float* __restrict__ x,
    const float* __restrict__ w1, const float* __restrict__ b1,
    const float* __restrict__ w2, const float* __restrict__ b2,
    const float* __restrict__ w3, const float* __restrict__ b3,
    float* __restrict__ feat, float* __restrict__ norms){
  __shared__ float h1[64];
  __shared__ float h2[128];
  __shared__ float nr[2];
  int p = blockIdx.x, t = threadIdx.x;
  float x0 = x[p * 3 + 0], x1 = x[p * 3 + 1], x2 = x[p * 3 + 2];
  if (t < 64){
    float a = x0 * w1[t] + x1 * w1[64 + t] + x2 * w1[128 + t] + b1[t];
    h1[t] = fmaxf(a, 0.f);
  }
  __syncthreads();
  float a = b2[t];
  #pragma unroll 8
  for (int k = 0; k < 64; k++) a = fmaf(h1[k], w2[k * 128 + t], a);
  h2[t] = fmaxf(a, 0.f);
  __syncthreads();
  float o = b3[t];
  #pragma unroll 8
  for (int k = 0; k < 128; k++) o = fmaf(h2[k], w3[k * 128 + t], o);
  feat[(size_t)p * FD + t] = o;
  float q = o * o;
  #pragma unroll
  for (int off = 32; off; off >>= 1) q += __shfl_down(q, off);
  if ((t & 63) == 0) nr[t >> 6] = q;
  __syncthreads();
  if (t == 0) norms[p] = nr[0] + nr[1];
}

__device__ __forceinline__ int swz(int r, int k4){
  return r * FD + ((k4 ^ ((r >> 2) & 7)) << 2);
}

__global__ __launch_bounds__(256) void score_kernel(const float* __restrict__ af,
    const float* __restrict__ bf, const float* __restrict__ na, const float* __restrict__ nb,
    const Consts* __restrict__ C, float* __restrict__ S,
    unsigned* __restrict__ rowmax, unsigned* __restrict__ rowmin){
  __shared__ float As[64 * FD];
  __shared__ float Bs[64 * FD];
  int i0 = blockIdx.y * 64, j0 = blockIdx.x * 64;
  int tid = threadIdx.x;
  #pragma unroll
  for (int cc = 0; cc < 8; cc++){
    int lin = cc * 1024 + tid * 4;
    int r = lin >> 7;
    int k = lin & 127;
    int k4 = k >> 2;
    float4 av = *(const float4*)&af[(size_t)(i0 + r) * FD + k];
    float4 bv = *(const float4*)&bf[(size_t)(j0 + r) * FD + k];
    *(float4*)&As[swz(r, k4)] = av;
    *(float4*)&Bs[swz(r, k4)] = bv;
  }
  __syncthreads();
  int tx = tid & 15, ty = tid >> 4;
  int r0 = ty * 4, c0 = tx * 4;
  float acc[4][4];
  #pragma unroll
  for (int a_ = 0; a_ < 4; a_++)
    #pragma unroll
    for (int b_ = 0; b_ < 4; b_++) acc[a_][b_] = 0.f;
  #pragma unroll 4
  for (int k = 0; k < FD; k += 4){
    float4 av[4], bv[4];
    #pragma unroll
    for (int q = 0; q < 4; q++){
      av[q] = *(const float4*)&As[swz(r0 + q, k >> 2)];
      bv[q] = *(const float4*)&Bs[swz(c0 + q, k >> 2)];
    }
    #pragma unroll
    for (int a_ = 0; a_ < 4; a_++)
      #pragma unroll
      for (int b_ = 0; b_ < 4; b_++){
        acc[a_][b_] = fmaf(av[a_].x, bv[b_].x, acc[a_][b_]);
        acc[a_][b_] = fmaf(av[a_].y, bv[b_].y, acc[a_][b_]);
        acc[a_][b_] = fmaf(av[a_].z, bv[b_].z, acc[a_][b_]);
        acc[a_][b_] = fmaf(av[a_].w, bv[b_].w, acc[a_][b_]);
      }
  }
  float inv_t = C->inv_temp;
  float rmx[4], rmn[4];
  #pragma unroll
  for (int a_ = 0; a_ < 4; a_++){
    float nai = na[i0 + r0 + a_];
    float4 out;
    float* op = &out.x;
    float tmx = -INFINITY, tmn = INFINITY;
    #pragma unroll
    for (int b_ = 0; b_ < 4; b_++){
      float d2 = nai + nb[j0 + c0 + b_] - 2.0f * acc[a_][b_];
      d2 = fmaxf(d2, 0.f);
      float sc = -sqrtf(d2) * inv_t;
      op[b_] = sc;
      tmx = fmaxf(tmx, sc);
      tmn = fminf(tmn, sc);
    }
    rmx[a_] = tmx; rmn[a_] = tmn;
    *(float4*)&S[(size_t)(i0 + r0 + a_) * MM + j0 + c0] = out;
  }
  #pragma unroll
  for (int off = 8; off; off >>= 1){
    #pragma unroll
    for (int a_ = 0; a_ < 4; a_++){
      rmx[a_] = fmaxf(rmx[a_], __shfl_xor(rmx[a_], off));
      rmn[a_] = fminf(rmn[a_], __shfl_xor(rmn[a_], off));
    }
  }
  if (tx == 0){
    #pragma unroll
    for (int a_ = 0; a_ < 4; a_++){
      atomicMax(&rowmax[i0 + r0 + a_], fenc(rmx[a_]));
      atomicMin(&rowmin[i0 + r0 + a_], fenc(rmn[a_]));
    }
  }
}

__global__ __launch_bounds__(256) void smax_kernel(const unsigned* __restrict__ rowmax,
                                                   unsigned* __restrict__ se){
  __shared__ unsigned wm[4];
  int t = threadIdx.x;
  unsigned m = 0u;
  #pragma unroll
  for (int k = 0; k < 32; k++){
    unsigned x = rowmax[k * 256 + t];
    m = m > x ? m : x;
  }
  #pragma unroll
  for (int off = 32; off; off >>= 1){
    unsigned x = __shfl_xor(m, off);
    m = m > x ? m : x;
  }
  if ((t & 63) == 0) wm[t >> 6] = m;
  __syncthreads();
  if (t == 0){
    unsigned r = wm[0];
    for (int w = 1; w < 4; w++) r = r > wm[w] ? r : wm[w];
    *se = r;
  }
}

__global__ __launch_bounds__(256) void quant_kernel(const float* __restrict__ S,
    const unsigned* __restrict__ rowmax, const unsigned* __restrict__ rowmin,
    const unsigned* __restrict__ se,
    ushort_t* __restrict__ Q, float* __restrict__ base, float* __restrict__ qstep){
  int i = blockIdx.y, t = threadIdx.x;
  float R = fdec(rowmax[i]);
  float range = fmaxf(R - fdec(rowmin[i]), 1e-5f);
  float step = range / 65535.0f;
  float invstep = 65535.0f / range;
  if (blockIdx.x == 0 && t == 0){
    base[i] = R - fdec(*se) - 65535.0f * step;
    qstep[i] = step;
  }
  int j0 = blockIdx.x * 2048 + t * 8;
  const float4 a = *(const float4*)&S[(size_t)i * MM + j0];
  const float4 b = *(const float4*)&S[(size_t)i * MM + j0 + 4];
  float xs[8] = {a.x, a.y, a.z, a.w, b.x, b.y, b.z, b.w};
  uint4 qv;
  ushort_t* qp = (ushort_t*)&qv;
  #pragma unroll
  for (int k = 0; k < 8; k++){
    float fq = (xs[k] - R) * invstep + 65535.5f;
    fq = fminf(fmaxf(fq, 0.f), 65535.f);
    qp[k] = (ushort_t)(int)fq;
  }
  *(uint4*)&Q[(size_t)i * MM + j0] = qv;
}

// rowq with convergence instrumentation (validated math unchanged)
__global__ __launch_bounds__(256) void rowq_kernel(const ushort_t* __restrict__ Q,
    const float* __restrict__ v, float* __restrict__ u, const float* __restrict__ base,
    const float* __restrict__ qstep, const Consts* __restrict__ C,
    const unsigned* __restrict__ convz, unsigned* __restrict__ notConv){
  if (convz[0]) return;
  __shared__ float rm[4], rs[4];
  int i = blockIdx.x, t = threadIdx.x;
  if (i == NN){
    float m = -INFINITY, s = 0.f;
    for (int j = t; j <= MM; j += 256) lse_add(m, s, v[j]);
    block_lse_reduce(m, s, rm, rs, t);
    if (t == 0){
      float uo = u[NN];
      float un = C->lmu_dust - (C->B + m + __logf(s));
      u[NN] = un;
      if (fabsf(un - uo) > RELTHR * (fabsf(un) + 1.0f)) *notConv = 1u;
    }
    return;
  }
  float step = qstep[i];
  const uint4* Qr = (const uint4*)(Q + (size_t)i * MM);
  const float4* Vr = (const float4*)v;
  uint4 q[4];
  #pragma unroll
  for (int c = 0; c < 4; c++) q[c] = Qr[c * 256 + t];
  float4 va[8];
  #pragma unroll
  for (int c = 0; c < 4; c++){
    va[2 * c]     = Vr[(c * 256 + t) * 2];
    va[2 * c + 1] = Vr[(c * 256 + t) * 2 + 1];
  }
  float x[32];
  float m = -INFINITY;
  #pragma unroll
  for (int c = 0; c < 4; c++){
    const ushort_t* qs = (const ushort_t*)&q[c];
    const float* vf = (const float*)&va[2 * c];
    #pragma unroll
    for (int k = 0; k < 8; k++){
      float xx = fmaf((float)qs[k], step, vf[k]);
      x[c * 8 + k] = xx;
      m = fmaxf(m, xx);
    }
  }
  #pragma unroll
  for (int off = 32; off; off >>= 1) m = fmaxf(m, __shfl_xor(m, off));
  if ((t & 63) == 0) rm[t >> 6] = m;
  __syncthreads();
  m = fmaxf(fmaxf(rm[0], rm[1]), fmaxf(rm[2], rm[3]));
  float s = 0.f;
  #pragma unroll
  for (int k = 0; k < 32; k++) s += __expf(x[k] - m);
  #pragma unroll
  for (int off = 32; off; off >>= 1) s += __shfl_xor(s, off);
  if ((t & 63) == 0) rs[t >> 6] = s;
  __syncthreads();
  if (t == 0){
    s = rs[0] + rs[1] + rs[2] + rs[3];
    float mm = base[i] + m;
    float x2 = C->B + v[MM];
    float nm = fmaxf(mm, x2);
    float s2 = s * __expf(mm - nm) + __expf(x2 - nm);
    float lmu = (i < C->overlap) ? C->lmu_main : C->lmu_eps;
    float uo = u[i];
    float un = lmu - (nm + __logf(s2));
    u[i] = un;
    if (fabsf(un - uo) > RELTHR * (fabsf(un) + 1.0f)) *notConv = 1u;
  }
}

__global__ __launch_bounds__(256) void colpq_kernel(const ushort_t* __restrict__ Q,
    const float* __restrict__ u, const float* __restrict__ base,
    const float* __restrict__ qstep, float* __restrict__ pm, float* __restrict__ ps,
    const unsigned* __restrict__ convz){
  if (convz[0]) return;
  int t = threadIdx.x;
  int j0 = blockIdx.x * 1024 + t * 4;
  int i0 = blockIdx.y * 64;
  float m0 = -INFINITY, m1 = -INFINITY, m2 = -INFINITY, m3 = -INFINITY;
  float s0 = 0.f, s1 = 0.f, s2 = 0.f, s3 = 0.f;
  #pragma unroll 4
  for (int r = 0; r < 64; r++){
    int i = i0 + r;
    float c = base[i] + u[i];
    float st = qstep[i];
    uint2 q = *(const uint2*)&Q[(size_t)i * MM + j0];
    float q0 = (float)(q.x & 0xFFFFu);
    float q1 = (float)(q.x >> 16);
    float q2 = (float)(q.y & 0xFFFFu);
    float q3 = (float)(q.y >> 16);
    { float x = fmaf(q0, st, c); float nm = fmaxf(m0, x); s0 = s0 * __expf(m0 - nm) + __expf(x - nm); m0 = nm; }
    { float x = fmaf(q1, st, c); float nm = fmaxf(m1, x); s1 = s1 * __expf(m1 - nm) + __expf(x - nm); m1 = nm; }
    { float x = fmaf(q2, st, c); float nm = fmaxf(m2, x); s2 = s2 * __expf(m2 - nm) + __expf(x - nm); m2 = nm; }
    { float x = fmaf(q3, st, c); float nm = fmaxf(m3, x); s3 = s3 * __expf(m3 - nm) + __expf(x - nm); m3 = nm; }
  }
  size_t o = (size_t)blockIdx.y * MM + j0;
  *(float4*)&pm[o] = make_float4(m0, m1, m2, m3);
  *(float4*)&ps[o] = make_float4(s0, s1, s2, s3);
}

// colc: convz/convSet null in polish phase
__global__ __launch_bounds__(256) void colc_kernel(const float* __restrict__ pm,
    const float* __restrict__ ps, const float* __restrict__ u, float* __restrict__ v,
    const Consts* __restrict__ C,
    const unsigned* __restrict__ convz, unsigned* __restrict__ notConv,
    unsigned* __restrict__ convSet){
  if (convz && convz[0]) return;
  __shared__ float rm[4], rs[4];
  int b = blockIdx.x, t = threadIdx.x;
  if (b < 128){
    int col = b * 64 + (t >> 2);
    int seg = t & 3;
    float m = -INFINITY, s = 0.f;
    #pragma unroll 8
    for (int k = 0; k < 32; k++){
      int rc = seg * 32 + k;
      lse_merge(m, s, pm[(size_t)rc * MM + col], ps[(size_t)rc * MM + col]);
    }
    { float mo = __shfl_down(m, 2, 4); float so = __shfl_down(s, 2, 4); lse_merge(m, s, mo, so); }
    { float mo = __shfl_down(m, 1, 4); float so = __shfl_down(s, 1, 4); lse_merge(m, s, mo, so); }
    if (seg == 0){
      lse_add(m, s, C->B + u[NN]);
      float lnu = (col < C->overlap) ? C->lnu_main : C->lnu_eps;
      v[col] = lnu - (m + __logf(s));
    }
  } else {
    float m = -INFINITY, s = 0.f;
    for (int i = t; i <= NN; i += 256) lse_add(m, s, u[i]);
    block_lse_reduce(m, s, rm, rs, t);
    if (t == 0){
      v[MM] = C->lnu_dust - (C->B + m + __logf(s));
      if (convSet){
        if (*notConv == 0u) *convSet = 1u;
        *notConv = 0u;
      }
    }
  }
}

// ---- fp32 iteration kernels (polish + fallback) ----
__global__ __launch_bounds__(256) void row_kernel(const float* __restrict__ S,
    const float* __restrict__ v, float* __restrict__ u,
    const Consts* __restrict__ C, const unsigned* __restrict__ se){
  __shared__ float rm[4], rs[4];
  int i = blockIdx.x, t = threadIdx.x;
  float smax = fdec(*se);
  if (i == NN){
    float m = -INFINITY, s = 0.f;
    for (int j = t; j <= MM; j += 256) lse_add(m, s, v[j]);
    block_lse_reduce(m, s, rm, rs, t);
    if (t == 0) u[NN] = C->lmu_dust - (C->B + m + __logf(s));
    return;
  }
  const float4* Sr = (const float4*)(S + (size_t)i * MM);
  const float4* Vr = (const float4*)v;
  float4 val[8];
  float m = -INFINITY;
  #pragma unroll
  for (int c = 0; c < 8; c++){
    float4 a = Sr[c * 256 + t];
    float4 w = Vr[c * 256 + t];
    float4 x;
    x.x = a.x - smax + w.x;
    x.y = a.y - smax + w.y;
    x.z = a.z - smax + w.z;
    x.w = a.w - smax + w.w;
    val[c] = x;
    m = fmaxf(m, fmaxf(fmaxf(x.x, x.y), fmaxf(x.z, x.w)));
  }
  #pragma unroll
  for (int off = 32; off; off >>= 1) m = fmaxf(m, __shfl_xor(m, off));
  if ((t & 63) == 0) rm[t >> 6] = m;
  __syncthreads();
  m = fmaxf(fmaxf(rm[0], rm[1]), fmaxf(rm[2], rm[3]));
  float s = 0.f;
  #pragma unroll
  for (int c = 0; c < 8; c++){
    s += __expf(val[c].x - m) + __expf(val[c].y - m)
       + __expf(val[c].z - m) + __expf(val[c].w - m);
  }
  #pragma unroll
  for (int off = 32; off; off >>= 1) s += __shfl_xor(s, off);
  if ((t & 63) == 0) rs[t >> 6] = s;
  __syncthreads();
  if (t == 0){
    s = rs[0] + rs[1] + rs[2] + rs[3];
    float x = C->B + v[MM];
    float nm = fmaxf(m, x);
    float s2 = s * __expf(m - nm) + __expf(x - nm);
    float lmu = (i < C->overlap) ? C->lmu_main : C->lmu_eps;
    u[i] = lmu - (nm + __logf(s2));
  }
}

__global__ __launch_bounds__(256) void colp_kernel(const float* __restrict__ S,
    const float* __restrict__ u, float* __restrict__ pm, float* __restrict__ ps,
    const unsigned* __restrict__ se){
  float smax = fdec(*se);
  int j0 = blockIdx.x * 1024 + threadIdx.x * 4;
  int i0 = blockIdx.y * 64;
  float m0 = -INFINITY, m1 = -INFINITY, m2 = -INFINITY, m3 = -INFINITY;
  float s0 = 0.f, s1 = 0.f, s2 = 0.f, s3 = 0.f;
  #pragma unroll 4
  for (int r = 0; r < 64; r++){
    int i = i0 + r;
    float c = u[i] - smax;
    float4 a = *(const float4*)&S[(size_t)i * MM + j0];
    { float x = a.x + c; float nm = fmaxf(m0, x); s0 = s0 * __expf(m0 - nm) + __expf(x - nm); m0 = nm; }
    { float x = a.y + c; float nm = fmaxf(m1, x); s1 = s1 * __expf(m1 - nm) + __expf(x - nm); m1 = nm; }
    { float x = a.z + c; float nm = fmaxf(m2, x); s2 = s2 * __expf(m2 - nm) + __expf(x - nm); m2 = nm; }
    { float x = a.w + c; float nm = fmaxf(m3, x); s3 = s3 * __expf(m3 - nm) + __expf(x - nm); m3 = nm; }
  }
  size_t o = (size_t)blockIdx.y * MM + j0;
  *(float4*)&pm[o] = make_float4(m0, m1, m2, m3);
  *(float4*)&ps[o] = make_float4(s0, s1, s2, s3);
}

__global__ __launch_bounds__(256) void trans_kernel(float* __restrict__ S,
    const float* __restrict__ u, const float* __restrict__ v,
    const unsigned* __restrict__ se){
  size_t lin = ((size_t)blockIdx.x * 256 + threadIdx.x) * 4;
  int i = (int)(lin >> 13);
  int j = (int)(lin & (size_t)(MM - 1));
  float c = u[i] - fdec(*se);
  float4 a = *(float4*)&S[lin];
  const float4 w = *(const float4*)&v[j];
  a.x = __expf(a.x + c + w.x);
  a.y = __expf(a.y + c + w.y);
  a.z = __expf(a.z + c + w.z);
  a.w = __expf(a.w + c + w.w);
  *(float4*)&S[lin] = a;
}

__global__ __launch_bounds__(256) void dustbin_kernel(float* __restrict__ out,
    const float* __restrict__ u, const float* __restrict__ v,
    const Consts* __restrict__ C){
  int idx = blockIdx.x * 256 + threadIdx.x;
  float B = C->B;
  if (idx < NN){
    out[(size_t)NN * MM + idx] = __expf(B + u[idx] + v[MM]);
  } else {
    int j = idx - NN;
    out[(size_t)NN * MM + NN + j] = __expf(B + u[NN] + v[j]);
  }
}

extern "C" void kernel_launch(void* const* d_in, const int* in_sizes, int n_in,
                              void* d_out, int out_size, void* d_ws, size_t ws_size,
                              hipStream_t stream){
  const float* source = (const float*)d_in[0];
  const float* target = (const float*)d_in[1];
  const float* sw1 = (const float*)d_in[2];
  const float* sb1 = (const float*)d_in[3];
  const float* sw2 = (const float*)d_in[4];
  const float* sb2 = (const float*)d_in[5];
  const float* sw3 = (const float*)d_in[6];
  const float* sb3 = (const float*)d_in[7];
  const float* tw1 = (const float*)d_in[8];
  const float* tb1 = (const float*)d_in[9];
  const float* tw2 = (const float*)d_in[10];
  const float* tb2 = (const float*)d_in[11];
  const float* tw3 = (const float*)d_in[12];
  const float* tb3 = (const float*)d_in[13];
  const float* lt  = (const float*)d_in[14];
  const float* db  = (const float*)d_in[15];
  const int*   ovp = (const int*)d_in[16];

  float* S  = (float*)d_out;
  float* ws = (float*)d_ws;
  Consts* C        = (Consts*)ws;              // [0,32)
  unsigned* se     = (unsigned*)(ws + 32);     // [32,64)
  unsigned* rowmax = (unsigned*)(ws + 64);     // 8192
  unsigned* rowmin = (unsigned*)(ws + 8256);   // 8192
  float* u    = ws + 16448;                    // 8448
  float* v    = ws + 24896;                    // 8448 (8193 used)
  unsigned* conv    = (unsigned*)(ws + 33344); // [33344]
  unsigned* notConv = (unsigned*)(ws + 33345); // [33345]
  float* base = ws + 34432;                    // 8192
  float* qstep= ws + 42624;                    // 8192
  float* A0   = ws + 50816;
  float* sfeat = A0;
  float* tfeat = A0 + (size_t)NN * FD;
  float* na = A0 + 2 * (size_t)NN * FD;
  float* nb = na + NN;
  float* pm = A0;                              // aliases feats (dead after score)
  float* psum = A0 + (size_t)128 * MM;

  const size_t QOFF = 8657408;                 // bytes, == end of A0 region
  const size_t QBYTES = (size_t)NN * MM * 2;
  bool quant = (ws_size >= QOFF + QBYTES);
  ushort_t* Q = (ushort_t*)((char*)d_ws + QOFF);

  // zero u, v, conv flags (region [16448, 33408) floats)
  hipMemsetAsync(u, 0, sizeof(float) * (2 * 8448 + 64), stream);
  init_kernel<<<65, 256, 0, stream>>>(lt, db, ovp, C, se, rowmax, rowmin);
  mlp_kernel<<<NN, 128, 0, stream>>>(source, sw1, sb1, sw2, sb2, sw3, sb3, sfeat, na);
  mlp_kernel<<<MM, 128, 0, stream>>>(target, tw1, tb1, tw2, tb2, tw3, tb3, tfeat, nb);
  score_kernel<<<dim3(MM / 64, NN / 64), 256, 0, stream>>>(sfeat, tfeat, na, nb, C, S, rowmax, rowmin);
  smax_kernel<<<1, 256, 0, stream>>>(rowmax, se);

  if (quant){
    quant_kernel<<<dim3(4, NN), 256, 0, stream>>>(S, rowmax, rowmin, se, Q, base, qstep);
    for (int it = 0; it < NITER - NPOLISH; ++it){
      rowq_kernel<<<NN + 1, 256, 0, stream>>>(Q, v, u, base, qstep, C, conv, notConv);
      colpq_kernel<<<dim3(8, 128), 256, 0, stream>>>(Q, u, base, qstep, pm, psum, conv);
      colc_kernel<<<129, 256, 0, stream>>>(pm, psum, u, v, C, conv, notConv, conv);
    }
    for (int it = 0; it < NPOLISH; ++it){
      row_kernel<<<NN + 1, 256, 0, stream>>>(S, v, u, C, se);
      colp_kernel<<<dim3(8, 128), 256, 0, stream>>>(S, u, pm, psum, se);
      colc_kernel<<<129, 256, 0, stream>>>(pm, psum, u, v, C, nullptr, nullptr, nullptr);
    }
  } else {
    for (int it = 0; it < NITER; ++it){
      row_kernel<<<NN + 1, 256, 0, stream>>>(S, v, u, C, se);
      colp_kernel<<<dim3(8, 128), 256, 0, stream>>>(S, u, pm, psum, se);
      colc_kernel<<<129, 256, 0, stream>>>(pm, psum, u, v, C, nullptr, nullptr, nullptr);
    }
  }
  trans_kernel<<<(int)(((size_t)NN * MM) / 1024), 256, 0, stream>>>(S, u, v, se);
  dustbin_kernel<<<(2 * NN) / 256, 256, 0, stream>>>((float*)d_out, u, v, C);
}

// Round 15
// 7032.723 us; speedup vs baseline: 1.0071x; 1.0071x over previous
//
#include <hip/hip_runtime.h>
#include <math.h>

#define NN 8192
#define MM 8192
#define FD 128
#define NITER 100
#define NPOLISH 4

typedef unsigned short ushort_t;

struct Consts {
  float inv_temp, B;
  float lmu_main, lmu_eps, lmu_dust;
  float lnu_main, lnu_eps, lnu_dust;
  int overlap;
};

__device__ __forceinline__ unsigned fenc(float f){
  unsigned u = __float_as_uint(f);
  return (u & 0x80000000u) ? ~u : (u | 0x80000000u);
}
__device__ __forceinline__ float fdec(unsigned e){
  return __uint_as_float((e & 0x80000000u) ? (e ^ 0x80000000u) : ~e);
}
__device__ __forceinline__ void lse_add(float& m, float& s, float x){
  float nm = fmaxf(m, x);
  s = s * __expf(m - nm) + __expf(x - nm);
  m = nm;
}
__device__ __forceinline__ void lse_merge(float& m, float& s, float mo, float so){
  float nm = fmaxf(m, mo);
  s = s * __expf(m - nm) + so * __expf(mo - nm);
  m = nm;
}
__device__ __forceinline__ void block_lse_reduce(float& m, float& s, float* rm, float* rs, int t){
  #pragma unroll
  for (int off = 32; off; off >>= 1){
    float mo = __shfl_down(m, off);
    float so = __shfl_down(s, off);
    lse_merge(m, s, mo, so);
  }
  if ((t & 63) == 0){ rm[t >> 6] = m; rs[t >> 6] = s; }
  __syncthreads();
  if (t == 0){
    m = rm[0]; s = rs[0];
    #pragma unroll
    for (int w = 1; w < 4; w++) lse_merge(m, s, rm[w], rs[w]);
  }
}

// init: rowmax -> enc(-inf), rowmin -> enc(+inf), consts, se
__global__ void init_kernel(const float* lt, const float* db, const int* ovp,
                            Consts* C, unsigned* se, unsigned* rowmax, unsigned* rowmin){
  int b = blockIdx.x, t = threadIdx.x;
  if (b < 32){ rowmax[b * 256 + t] = fenc(-INFINITY); return; }
  if (b < 64){ rowmin[(b - 32) * 256 + t] = fenc(INFINITY); return; }
  if (t == 0){
    float temp = fmaxf(expf(lt[0]), 1e-9f);
    C->inv_temp = 1.0f / temp;
    C->B = db[0];
    int ov = ovp[0];
    C->overlap = ov;
    int us = NN - ov > 0 ? NN - ov : 0;
    int ut = MM - ov > 0 ? MM - ov : 0;
    float mud = (float)fmax((double)ut * 0.3, 1e-9);
    float nud = (float)fmax((double)us * 0.3, 1e-9);
    int ones_mu = us > 0 ? ov : NN;
    int ones_nu = ut > 0 ? ov : MM;
    double Zmu = (double)ones_mu + (double)(NN - ones_mu) * 1e-9 + (double)mud;
    double Znu = (double)ones_nu + (double)(MM - ones_nu) * 1e-9 + (double)nud;
    C->lmu_main = (float)log(1.0 / Zmu);
    C->lmu_eps  = (float)log(1e-9 / Zmu);
    C->lmu_dust = (float)log((double)mud / Zmu);
    C->lnu_main = (float)log(1.0 / Znu);
    C->lnu_eps  = (float)log(1e-9 / Znu);
    C->lnu_dust = (float)log((double)nud / Znu);
    *se = 0u;
  }
}

__global__ __launch_bounds__(128) void mlp_kernel(const float* __restrict__ x,
    const float* __restrict__ w1, const float* __restrict__ b1,
    const float* __restrict__ w2, const float* __restrict__ b2,
    const float* __restrict__ w3, const float* __restrict__ b3,
    float* __restrict__ feat, float* __restrict__ norms){
  __shared__ float h1[64];
  __shared__ float h2[128];
  __shared__ float nr[2];
  int p = blockIdx.x, t = threadIdx.x;
  float x0 = x[p * 3 + 0], x1 = x[p * 3 + 1], x2 = x[p * 3 + 2];
  if (t < 64){
    float a = x0 * w1[t] + x1 * w1[64 + t] + x2 * w1[128 + t] + b1[t];
    h1[t] = fmaxf(a, 0.f);
  }
  __syncthreads();
  float a = b2[t];
  #pragma unroll 8
  for (int k = 0; k < 64; k++) a = fmaf(h1[k], w2[k * 128 + t], a);
  h2[t] = fmaxf(a, 0.f);
  __syncthreads();
  float o = b3[t];
  #pragma unroll 8
  for (int k = 0; k < 128; k++) o = fmaf(h2[k], w3[k * 128 + t], o);
  feat[(size_t)p * FD + t] = o;
  float q = o * o;
  #pragma unroll
  for (int off = 32; off; off >>= 1) q += __shfl_down(q, off);
  if ((t & 63) == 0) nr[t >> 6] = q;
  __syncthreads();
  if (t == 0) norms[p] = nr[0] + nr[1];
}

__device__ __forceinline__ int swz(int r, int k4){
  return r * FD + ((k4 ^ ((r >> 2) & 7)) << 2);
}

__global__ __launch_bounds__(256) void score_kernel(const float* __restrict__ af,
    const float* __restrict__ bf, const float* __restrict__ na, const float* __restrict__ nb,
    const Consts* __restrict__ C, float* __restrict__ S,
    unsigned* __restrict__ rowmax, unsigned* __restrict__ rowmin){
  __shared__ float As[64 * FD];
  __shared__ float Bs[64 * FD];
  int i0 = blockIdx.y * 64, j0 = blockIdx.x * 64;
  int tid = threadIdx.x;
  #pragma unroll
  for (int cc = 0; cc < 8; cc++){
    int lin = cc * 1024 + tid * 4;
    int r = lin >> 7;
    int k = lin & 127;
    int k4 = k >> 2;
    float4 av = *(const float4*)&af[(size_t)(i0 + r) * FD + k];
    float4 bv = *(const float4*)&bf[(size_t)(j0 + r) * FD + k];
    *(float4*)&As[swz(r, k4)] = av;
    *(float4*)&Bs[swz(r, k4)] = bv;
  }
  __syncthreads();
  int tx = tid & 15, ty = tid >> 4;
  int r0 = ty * 4, c0 = tx * 4;
  float acc[4][4];
  #pragma unroll
  for (int a_ = 0; a_ < 4; a_++)
    #pragma unroll
    for (int b_ = 0; b_ < 4; b_++) acc[a_][b_] = 0.f;
  #pragma unroll 4
  for (int k = 0; k < FD; k += 4){
    float4 av[4], bv[4];
    #pragma unroll
    for (int q = 0; q < 4; q++){
      av[q] = *(const float4*)&As[swz(r0 + q, k >> 2)];
      bv[q] = *(const float4*)&Bs[swz(c0 + q, k >> 2)];
    }
    #pragma unroll
    for (int a_ = 0; a_ < 4; a_++)
      #pragma unroll
      for (int b_ = 0; b_ < 4; b_++){
        acc[a_][b_] = fmaf(av[a_].x, bv[b_].x, acc[a_][b_]);
        acc[a_][b_] = fmaf(av[a_].y, bv[b_].y, acc[a_][b_]);
        acc[a_][b_] = fmaf(av[a_].z, bv[b_].z, acc[a_][b_]);
        acc[a_][b_] = fmaf(av[a_].w, bv[b_].w, acc[a_][b_]);
      }
  }
  float inv_t = C->inv_temp;
  float rmx[4], rmn[4];
  #pragma unroll
  for (int a_ = 0; a_ < 4; a_++){
    float nai = na[i0 + r0 + a_];
    float4 out;
    float* op = &out.x;
    float tmx = -INFINITY, tmn = INFINITY;
    #pragma unroll
    for (int b_ = 0; b_ < 4; b_++){
      float d2 = nai + nb[j0 + c0 + b_] - 2.0f * acc[a_][b_];
      d2 = fmaxf(d2, 0.f);
      float sc = -sqrtf(d2) * inv_t;
      op[b_] = sc;
      tmx = fmaxf(tmx, sc);
      tmn = fminf(tmn, sc);
    }
    rmx[a_] = tmx; rmn[a_] = tmn;
    *(float4*)&S[(size_t)(i0 + r0 + a_) * MM + j0 + c0] = out;
  }
  #pragma unroll
  for (int off = 8; off; off >>= 1){
    #pragma unroll
    for (int a_ = 0; a_ < 4; a_++){
      rmx[a_] = fmaxf(rmx[a_], __shfl_xor(rmx[a_], off));
      rmn[a_] = fminf(rmn[a_], __shfl_xor(rmn[a_], off));
    }
  }
  if (tx == 0){
    #pragma unroll
    for (int a_ = 0; a_ < 4; a_++){
      atomicMax(&rowmax[i0 + r0 + a_], fenc(rmx[a_]));
      atomicMin(&rowmin[i0 + r0 + a_], fenc(rmn[a_]));
    }
  }
}

__global__ __launch_bounds__(256) void smax_kernel(const unsigned* __restrict__ rowmax,
                                                   unsigned* __restrict__ se){
  __shared__ unsigned wm[4];
  int t = threadIdx.x;
  unsigned m = 0u;
  #pragma unroll
  for (int k = 0; k < 32; k++){
    unsigned x = rowmax[k * 256 + t];
    m = m > x ? m : x;
  }
  #pragma unroll
  for (int off = 32; off; off >>= 1){
    unsigned x = __shfl_xor(m, off);
    m = m > x ? m : x;
  }
  if ((t & 63) == 0) wm[t >> 6] = m;
  __syncthreads();
  if (t == 0){
    unsigned r = wm[0];
    for (int w = 1; w < 4; w++) r = r > wm[w] ? r : wm[w];
    *se = r;
  }
}

// per-row full-range quant: step_i = (rowmax_i - rowmin_i)/65535, NO clamping
__global__ __launch_bounds__(256) void quant_kernel(const float* __restrict__ S,
    const unsigned* __restrict__ rowmax, const unsigned* __restrict__ rowmin,
    const unsigned* __restrict__ se,
    ushort_t* __restrict__ Q, float* __restrict__ base, float* __restrict__ qstep){
  int i = blockIdx.y, t = threadIdx.x;
  float R = fdec(rowmax[i]);
  float range = fmaxf(R - fdec(rowmin[i]), 1e-5f);
  float step = range / 65535.0f;
  float invstep = 65535.0f / range;
  if (blockIdx.x == 0 && t == 0){
    base[i] = R - fdec(*se) - 65535.0f * step;
    qstep[i] = step;
  }
  int j0 = blockIdx.x * 2048 + t * 8;
  const float4 a = *(const float4*)&S[(size_t)i * MM + j0];
  const float4 b = *(const float4*)&S[(size_t)i * MM + j0 + 4];
  float xs[8] = {a.x, a.y, a.z, a.w, b.x, b.y, b.z, b.w};
  uint4 qv;
  ushort_t* qp = (ushort_t*)&qv;
  #pragma unroll
  for (int k = 0; k < 8; k++){
    float fq = (xs[k] - R) * invstep + 65535.5f;
    fq = fminf(fmaxf(fq, 0.f), 65535.f);
    qp[k] = (ushort_t)(int)fq;
  }
  *(uint4*)&Q[(size_t)i * MM + j0] = qv;
}

__global__ __launch_bounds__(256) void rowq_kernel(const ushort_t* __restrict__ Q,
    const float* __restrict__ v, float* __restrict__ u, const float* __restrict__ base,
    const float* __restrict__ qstep, const Consts* __restrict__ C){
  __shared__ float rm[4], rs[4];
  int i = blockIdx.x, t = threadIdx.x;
  if (i == NN){
    float m = -INFINITY, s = 0.f;
    for (int j = t; j <= MM; j += 256) lse_add(m, s, v[j]);
    block_lse_reduce(m, s, rm, rs, t);
    if (t == 0) u[NN] = C->lmu_dust - (C->B + m + __logf(s));
    return;
  }
  float step = qstep[i];
  const uint4* Qr = (const uint4*)(Q + (size_t)i * MM);
  const float4* Vr = (const float4*)v;
  uint4 q[4];
  #pragma unroll
  for (int c = 0; c < 4; c++) q[c] = Qr[c * 256 + t];
  float4 va[8];
  #pragma unroll
  for (int c = 0; c < 4; c++){
    va[2 * c]     = Vr[(c * 256 + t) * 2];
    va[2 * c + 1] = Vr[(c * 256 + t) * 2 + 1];
  }
  float x[32];
  float m = -INFINITY;
  #pragma unroll
  for (int c = 0; c < 4; c++){
    const ushort_t* qs = (const ushort_t*)&q[c];
    const float* vf = (const float*)&va[2 * c];
    #pragma unroll
    for (int k = 0; k < 8; k++){
      float xx = fmaf((float)qs[k], step, vf[k]);
      x[c * 8 + k] = xx;
      m = fmaxf(m, xx);
    }
  }
  #pragma unroll
  for (int off = 32; off; off >>= 1) m = fmaxf(m, __shfl_xor(m, off));
  if ((t & 63) == 0) rm[t >> 6] = m;
  __syncthreads();
  m = fmaxf(fmaxf(rm[0], rm[1]), fmaxf(rm[2], rm[3]));
  float s = 0.f;
  #pragma unroll
  for (int k = 0; k < 32; k++) s += __expf(x[k] - m);
  #pragma unroll
  for (int off = 32; off; off >>= 1) s += __shfl_xor(s, off);
  if ((t & 63) == 0) rs[t >> 6] = s;
  __syncthreads();
  if (t == 0){
    s = rs[0] + rs[1] + rs[2] + rs[3];
    float mm = base[i] + m;
    float x2 = C->B + v[MM];
    float nm = fmaxf(mm, x2);
    float s2 = s * __expf(mm - nm) + __expf(x2 - nm);
    float lmu = (i < C->overlap) ? C->lmu_main : C->lmu_eps;
    u[i] = lmu - (nm + __logf(s2));
  }
}

// grid (8,128): 1024 blocks (4/CU). 4 cols/thread (uint2), 64 rows. 128 chunks.
__global__ __launch_bounds__(256) void colpq_kernel(const ushort_t* __restrict__ Q,
    const float* __restrict__ u, const float* __restrict__ base,
    const float* __restrict__ qstep, float* __restrict__ pm, float* __restrict__ ps){
  int t = threadIdx.x;
  int j0 = blockIdx.x * 1024 + t * 4;
  int i0 = blockIdx.y * 64;
  float m0 = -INFINITY, m1 = -INFINITY, m2 = -INFINITY, m3 = -INFINITY;
  float s0 = 0.f, s1 = 0.f, s2 = 0.f, s3 = 0.f;
  #pragma unroll 4
  for (int r = 0; r < 64; r++){
    int i = i0 + r;
    float c = base[i] + u[i];
    float st = qstep[i];
    uint2 q = *(const uint2*)&Q[(size_t)i * MM + j0];
    float q0 = (float)(q.x & 0xFFFFu);
    float q1 = (float)(q.x >> 16);
    float q2 = (float)(q.y & 0xFFFFu);
    float q3 = (float)(q.y >> 16);
    { float x = fmaf(q0, st, c); float nm = fmaxf(m0, x); s0 = s0 * __expf(m0 - nm) + __expf(x - nm); m0 = nm; }
    { float x = fmaf(q1, st, c); float nm = fmaxf(m1, x); s1 = s1 * __expf(m1 - nm) + __expf(x - nm); m1 = nm; }
    { float x = fmaf(q2, st, c); float nm = fmaxf(m2, x); s2 = s2 * __expf(m2 - nm) + __expf(x - nm); m2 = nm; }
    { float x = fmaf(q3, st, c); float nm = fmaxf(m3, x); s3 = s3 * __expf(m3 - nm) + __expf(x - nm); m3 = nm; }
  }
  size_t o = (size_t)blockIdx.y * MM + j0;
  *(float4*)&pm[o] = make_float4(m0, m1, m2, m3);
  *(float4*)&ps[o] = make_float4(s0, s1, s2, s3);
}

// 129 blocks: b<128 -> 64 cols/block, 4 threads/col x 32 chunks + shfl merge.
// b==128 -> dustbin v[MM].
__global__ __launch_bounds__(256) void colc_kernel(const float* __restrict__ pm,
    const float* __restrict__ ps, const float* __restrict__ u, float* __restrict__ v,
    const Consts* __restrict__ C){
  __shared__ float rm[4], rs[4];
  int b = blockIdx.x, t = threadIdx.x;
  if (b < 128){
    int col = b * 64 + (t >> 2);
    int seg = t & 3;
    float m = -INFINITY, s = 0.f;
    #pragma unroll 8
    for (int k = 0; k < 32; k++){
      int rc = seg * 32 + k;
      lse_merge(m, s, pm[(size_t)rc * MM + col], ps[(size_t)rc * MM + col]);
    }
    { float mo = __shfl_down(m, 2, 4); float so = __shfl_down(s, 2, 4); lse_merge(m, s, mo, so); }
    { float mo = __shfl_down(m, 1, 4); float so = __shfl_down(s, 1, 4); lse_merge(m, s, mo, so); }
    if (seg == 0){
      lse_add(m, s, C->B + u[NN]);
      float lnu = (col < C->overlap) ? C->lnu_main : C->lnu_eps;
      v[col] = lnu - (m + __logf(s));
    }
  } else {
    float m = -INFINITY, s = 0.f;
    for (int i = t; i <= NN; i += 256) lse_add(m, s, u[i]);
    block_lse_reduce(m, s, rm, rs, t);
    if (t == 0) v[MM] = C->lnu_dust - (C->B + m + __logf(s));
  }
}

// ---- fp32 iteration kernels (polish + fallback) ----
__global__ __launch_bounds__(256) void row_kernel(const float* __restrict__ S,
    const float* __restrict__ v, float* __restrict__ u,
    const Consts* __restrict__ C, const unsigned* __restrict__ se){
  __shared__ float rm[4], rs[4];
  int i = blockIdx.x, t = threadIdx.x;
  float smax = fdec(*se);
  if (i == NN){
    float m = -INFINITY, s = 0.f;
    for (int j = t; j <= MM; j += 256) lse_add(m, s, v[j]);
    block_lse_reduce(m, s, rm, rs, t);
    if (t == 0) u[NN] = C->lmu_dust - (C->B + m + __logf(s));
    return;
  }
  const float4* Sr = (const float4*)(S + (size_t)i * MM);
  const float4* Vr = (const float4*)v;
  float4 val[8];
  float m = -INFINITY;
  #pragma unroll
  for (int c = 0; c < 8; c++){
    float4 a = Sr[c * 256 + t];
    float4 w = Vr[c * 256 + t];
    float4 x;
    x.x = a.x - smax + w.x;
    x.y = a.y - smax + w.y;
    x.z = a.z - smax + w.z;
    x.w = a.w - smax + w.w;
    val[c] = x;
    m = fmaxf(m, fmaxf(fmaxf(x.x, x.y), fmaxf(x.z, x.w)));
  }
  #pragma unroll
  for (int off = 32; off; off >>= 1) m = fmaxf(m, __shfl_xor(m, off));
  if ((t & 63) == 0) rm[t >> 6] = m;
  __syncthreads();
  m = fmaxf(fmaxf(rm[0], rm[1]), fmaxf(rm[2], rm[3]));
  float s = 0.f;
  #pragma unroll
  for (int c = 0; c < 8; c++){
    s += __expf(val[c].x - m) + __expf(val[c].y - m)
       + __expf(val[c].z - m) + __expf(val[c].w - m);
  }
  #pragma unroll
  for (int off = 32; off; off >>= 1) s += __shfl_xor(s, off);
  if ((t & 63) == 0) rs[t >> 6] = s;
  __syncthreads();
  if (t == 0){
    s = rs[0] + rs[1] + rs[2] + rs[3];
    float x = C->B + v[MM];
    float nm = fmaxf(m, x);
    float s2 = s * __expf(m - nm) + __expf(x - nm);
    float lmu = (i < C->overlap) ? C->lmu_main : C->lmu_eps;
    u[i] = lmu - (nm + __logf(s2));
  }
}

__global__ __launch_bounds__(256) void colp_kernel(const float* __restrict__ S,
    const float* __restrict__ u, float* __restrict__ pm, float* __restrict__ ps,
    const unsigned* __restrict__ se){
  float smax = fdec(*se);
  int j0 = blockIdx.x * 1024 + threadIdx.x * 4;
  int i0 = blockIdx.y * 64;
  float m0 = -INFINITY, m1 = -INFINITY, m2 = -INFINITY, m3 = -INFINITY;
  float s0 = 0.f, s1 = 0.f, s2 = 0.f, s3 = 0.f;
  #pragma unroll 4
  for (int r = 0; r < 64; r++){
    int i = i0 + r;
    float c = u[i] - smax;
    float4 a = *(const float4*)&S[(size_t)i * MM + j0];
    { float x = a.x + c; float nm = fmaxf(m0, x); s0 = s0 * __expf(m0 - nm) + __expf(x - nm); m0 = nm; }
    { float x = a.y + c; float nm = fmaxf(m1, x); s1 = s1 * __expf(m1 - nm) + __expf(x - nm); m1 = nm; }
    { float x = a.z + c; float nm = fmaxf(m2, x); s2 = s2 * __expf(m2 - nm) + __expf(x - nm); m2 = nm; }
    { float x = a.w + c; float nm = fmaxf(m3, x); s3 = s3 * __expf(m3 - nm) + __expf(x - nm); m3 = nm; }
  }
  size_t o = (size_t)blockIdx.y * MM + j0;
  *(float4*)&pm[o] = make_float4(m0, m1, m2, m3);
  *(float4*)&ps[o] = make_float4(s0, s1, s2, s3);
}

__global__ __launch_bounds__(256) void trans_kernel(float* __restrict__ S,
    const float* __restrict__ u, const float* __restrict__ v,
    const unsigned* __restrict__ se){
  size_t lin = ((size_t)blockIdx.x * 256 + threadIdx.x) * 4;
  int i = (int)(lin >> 13);
  int j = (int)(lin & (size_t)(MM - 1));
  float c = u[i] - fdec(*se);
  float4 a = *(float4*)&S[lin];
  const float4 w = *(const float4*)&v[j];
  a.x = __expf(a.x + c + w.x);
  a.y = __expf(a.y + c + w.y);
  a.z = __expf(a.z + c + w.z);
  a.w = __expf(a.w + c + w.w);
  *(float4*)&S[lin] = a;
}

__global__ __launch_bounds__(256) void dustbin_kernel(float* __restrict__ out,
    const float* __restrict__ u, const float* __restrict__ v,
    const Consts* __restrict__ C){
  int idx = blockIdx.x * 256 + threadIdx.x;
  float B = C->B;
  if (idx < NN){
    out[(size_t)NN * MM + idx] = __expf(B + u[idx] + v[MM]);
  } else {
    int j = idx - NN;
    out[(size_t)NN * MM + NN + j] = __expf(B + u[NN] + v[j]);
  }
}

extern "C" void kernel_launch(void* const* d_in, const int* in_sizes, int n_in,
                              void* d_out, int out_size, void* d_ws, size_t ws_size,
                              hipStream_t stream){
  const float* source = (const float*)d_in[0];
  const float* target = (const float*)d_in[1];
  const float* sw1 = (const float*)d_in[2];
  const float* sb1 = (const float*)d_in[3];
  const float* sw2 = (const float*)d_in[4];
  const float* sb2 = (const float*)d_in[5];
  const float* sw3 = (const float*)d_in[6];
  const float* sb3 = (const float*)d_in[7];
  const float* tw1 = (const float*)d_in[8];
  const float* tb1 = (const float*)d_in[9];
  const float* tw2 = (const float*)d_in[10];
  const float* tb2 = (const float*)d_in[11];
  const float* tw3 = (const float*)d_in[12];
  const float* tb3 = (const float*)d_in[13];
  const float* lt  = (const float*)d_in[14];
  const float* db  = (const float*)d_in[15];
  const int*   ovp = (const int*)d_in[16];

  float* S  = (float*)d_out;
  float* ws = (float*)d_ws;
  Consts* C        = (Consts*)ws;              // [0,32)
  unsigned* se     = (unsigned*)(ws + 32);     // [32,64)
  unsigned* rowmax = (unsigned*)(ws + 64);     // [64, 8256)
  unsigned* rowmin = (unsigned*)(ws + 8256);   // [8256, 16448)
  float* u    = ws + 16448;                    // 8448
  float* v    = ws + 24896;                    // 8448
  float* base = ws + 33344;                    // 8192
  float* qstep= ws + 41536;                    // 8192
  float* A0   = ws + 49728;
  float* sfeat = A0;
  float* tfeat = A0 + (size_t)NN * FD;
  float* na = A0 + 2 * (size_t)NN * FD;
  float* nb = na + NN;
  float* pm = A0;                              // aliases feats (dead after score)
  float* psum = A0 + (size_t)128 * MM;

  const size_t QOFF = 8653056;                 // bytes, 256-aligned, past float region
  const size_t QBYTES = (size_t)NN * MM * 2;
  bool quant = (ws_size >= QOFF + QBYTES);
  ushort_t* Q = (ushort_t*)((char*)d_ws + QOFF);

  hipMemsetAsync(u, 0, sizeof(float) * 2 * 8448, stream);
  init_kernel<<<65, 256, 0, stream>>>(lt, db, ovp, C, se, rowmax, rowmin);
  mlp_kernel<<<NN, 128, 0, stream>>>(source, sw1, sb1, sw2, sb2, sw3, sb3, sfeat, na);
  mlp_kernel<<<MM, 128, 0, stream>>>(target, tw1, tb1, tw2, tb2, tw3, tb3, tfeat, nb);
  score_kernel<<<dim3(MM / 64, NN / 64), 256, 0, stream>>>(sfeat, tfeat, na, nb, C, S, rowmax, rowmin);
  smax_kernel<<<1, 256, 0, stream>>>(rowmax, se);

  if (quant){
    quant_kernel<<<dim3(4, NN), 256, 0, stream>>>(S, rowmax, rowmin, se, Q, base, qstep);
    for (int it = 0; it < NITER - NPOLISH; ++it){
      rowq_kernel<<<NN + 1, 256, 0, stream>>>(Q, v, u, base, qstep, C);
      colpq_kernel<<<dim3(8, 128), 256, 0, stream>>>(Q, u, base, qstep, pm, psum);
      colc_kernel<<<129, 256, 0, stream>>>(pm, psum, u, v, C);
    }
    for (int it = 0; it < NPOLISH; ++it){
      row_kernel<<<NN + 1, 256, 0, stream>>>(S, v, u, C, se);
      colp_kernel<<<dim3(8, 128), 256, 0, stream>>>(S, u, pm, psum, se);
      colc_kernel<<<129, 256, 0, stream>>>(pm, psum, u, v, C);
    }
  } else {
    for (int it = 0; it < NITER; ++it){
      row_kernel<<<NN + 1, 256, 0, stream>>>(S, v, u, C, se);
      colp_kernel<<<dim3(8, 128), 256, 0, stream>>>(S, u, pm, psum, se);
      colc_kernel<<<129, 256, 0, stream>>>(pm, psum, u, v, C);
    }
  }
  trans_kernel<<<(int)(((size_t)NN * MM) / 1024), 256, 0, stream>>>(S, u, v, se);
  dustbin_kernel<<<(2 * NN) / 256, 256, 0, stream>>>((float*)d_out, u, v, C);
}